// Round 1
// baseline (2249.446 us; speedup 1.0000x reference)
//
#include <hip/hip_runtime.h>

constexpr int B_ = 8;
constexpr int N_ = 2048;
constexpr int K_ = 20;
constexpr float SLOPE_ = 0.2f;

__device__ __forceinline__ float lrelu(float v) { return v > 0.0f ? v : SLOPE_ * v; }

// Build Wp[2O x C]: rows [0,O) = Wd = W[:, :C]; rows [O,2O) = Wc - Wd = W[:, C:] - W[:, :C]
__global__ void prep_wp(const float* __restrict__ W, float* __restrict__ Wp, int O, int C) {
  int i = blockIdx.x * 256 + threadIdx.x;
  if (i >= 2 * O * C) return;
  int o = i / C, c = i - o * C;
  if (o < O)
    Wp[i] = W[o * 2 * C + c];
  else
    Wp[i] = W[(o - O) * 2 * C + C + c] - W[(o - O) * 2 * C + c];
}

// kNN: 8 queries per block, 256 threads. d2 kept in registers (8 q x 8 m per thread).
// Top-20 by iterative block argmin over packed (f32bits<<32 | m) -- smallest-index tiebreak.
template <int C>
__global__ __launch_bounds__(256) void knn_kernel(const float* __restrict__ xin, int stride,
                                                  int* __restrict__ idxo) {
  const int b = blockIdx.y;
  const int q0 = blockIdx.x * 8;
  const int tid = threadIdx.x;
  __shared__ float qf[8][C];
  __shared__ unsigned long long wred[4];

  for (int i = tid; i < 8 * C; i += 256) {
    int q = i / C, c = i - q * C;
    qf[q][c] = xin[(size_t)(b * N_ + q0 + q) * stride + c];
  }
  __syncthreads();

  float d2r[8][8];  // [q][j], m = j*256 + tid
  const float* xb = xin + (size_t)b * N_ * stride;
#pragma unroll
  for (int j = 0; j < 8; j++) {
    const int m = j * 256 + tid;
    const float* xr = xb + (size_t)m * stride;
    float acc[8];
#pragma unroll
    for (int q = 0; q < 8; q++) acc[q] = 0.0f;
    if constexpr (C % 4 == 0) {
      for (int cg = 0; cg < C; cg += 4) {
        float4 xv = *(const float4*)(xr + cg);
#pragma unroll
        for (int q = 0; q < 8; q++) {
          float4 qv = *(const float4*)(&qf[q][cg]);
          float a0 = xv.x - qv.x, a1 = xv.y - qv.y, a2 = xv.z - qv.z, a3 = xv.w - qv.w;
          acc[q] += a0 * a0 + a1 * a1 + a2 * a2 + a3 * a3;
        }
      }
    } else {
      for (int c = 0; c < C; c++) {
        float xv = xr[c];
#pragma unroll
        for (int q = 0; q < 8; q++) {
          float d = xv - qf[q][c];
          acc[q] += d * d;
        }
      }
    }
#pragma unroll
    for (int q = 0; q < 8; q++) d2r[q][j] = acc[q];
  }

  const int wid = tid >> 6;
  const int lane = tid & 63;
#pragma unroll
  for (int q = 0; q < 8; q++) {
    unsigned long long loc = ~0ull;
#pragma unroll
    for (int j = 0; j < 8; j++) {
      unsigned long long u =
          ((unsigned long long)__float_as_uint(d2r[q][j]) << 32) | (unsigned)(j * 256 + tid);
      loc = u < loc ? u : loc;
    }
    for (int t = 0; t < K_; t++) {
      unsigned long long u = loc;
#pragma unroll
      for (int off = 32; off > 0; off >>= 1) {
        unsigned long long v = __shfl_xor(u, off, 64);
        u = v < u ? v : u;
      }
      if (lane == 0) wred[wid] = u;
      __syncthreads();
      unsigned long long g = wred[0];
      g = wred[1] < g ? wred[1] : g;
      g = wred[2] < g ? wred[2] : g;
      g = wred[3] < g ? wred[3] : g;
      __syncthreads();
      if (loc == g) {  // exactly one winner (m embeds tid)
        int m = (int)(unsigned)(g & 0xffffffffull);
        idxo[(size_t)(b * N_ + q0 + q) * K_ + t] = m;
#pragma unroll
        for (int j = 0; j < 8; j++)
          if (j * 256 + tid == m) d2r[q][j] = __int_as_float(0x7f800000);
        loc = ~0ull;
#pragma unroll
        for (int j = 0; j < 8; j++) {
          unsigned long long u2 =
              ((unsigned long long)__float_as_uint(d2r[q][j]) << 32) | (unsigned)(j * 256 + tid);
          loc = u2 < loc ? u2 : loc;
        }
      }
    }
  }
}

// P[row, o'] = sum_c h[row, c] * Wp[o', c]   for o' in [0, 2O)
template <int C, int O2>
__global__ void proj_kernel(const float* __restrict__ hin, int stride,
                            const float* __restrict__ Wp, float* __restrict__ P) {
  const int nt = blockIdx.x * 16;
  const int o = blockIdx.y * blockDim.x + threadIdx.x;
  __shared__ float hs[16][C];
  for (int i = threadIdx.x; i < 16 * C; i += blockDim.x) {
    int r = i / C, c = i - r * C;
    hs[r][c] = hin[(size_t)(nt + r) * stride + c];
  }
  __syncthreads();
  float acc[16];
#pragma unroll
  for (int t = 0; t < 16; t++) acc[t] = 0.0f;
  const float* wr = Wp + (size_t)o * C;
  if constexpr (C % 4 == 0) {
    for (int cg = 0; cg < C; cg += 4) {
      float4 w = *(const float4*)(wr + cg);
#pragma unroll
      for (int t = 0; t < 16; t++) {
        float4 h = *(const float4*)(&hs[t][cg]);
        acc[t] += w.x * h.x + w.y * h.y + w.z * h.z + w.w * h.w;
      }
    }
  } else {
    for (int c = 0; c < C; c++) {
      float w = wr[c];
#pragma unroll
      for (int t = 0; t < 16; t++) acc[t] += w * hs[t][c];
    }
  }
#pragma unroll
  for (int t = 0; t < 16; t++) P[(size_t)(nt + t) * O2 + o] = acc[t];
}

// h_out[row, o] = lrelu( max_k P[b*N + idx[k], o] + P[row, O + o] + bias[o] )
template <int O>
__global__ void combine_kernel(const float* __restrict__ P, const int* __restrict__ idxo,
                               const float* __restrict__ bias, float* __restrict__ hout) {
  const int row = blockIdx.x;
  const int o = threadIdx.x;
  __shared__ int idxs[K_];
  if (o < K_) idxs[o] = idxo[(size_t)row * K_ + o];
  __syncthreads();
  const int base_row = (row >> 11) << 11;  // (row / N_) * N_
  float g = -3.4e38f;
#pragma unroll
  for (int k = 0; k < K_; k++) {
    float v = P[(size_t)(base_row + idxs[k]) * (2 * O) + o];
    g = fmaxf(g, v);
  }
  float ba = P[(size_t)row * (2 * O) + O + o];
  hout[(size_t)row * 512 + o] = lrelu(g + ba + bias[o]);
}

// Final: partial max over an n-chunk of dot(hcat[row], Wf[o]) -> part[(b*16+ns)*1024 + o]
__global__ __launch_bounds__(256) void final_kernel(const float* __restrict__ hcat,
                                                    const float* __restrict__ Wf,
                                                    float* __restrict__ part) {
  const int o = blockIdx.x * 256 + threadIdx.x;
  const int b = blockIdx.z;
  const int n0 = blockIdx.y * 128;
  __shared__ float hs[16][512];  // 32 KB
  const float* wr = Wf + (size_t)o * 512;
  float best = -3.4e38f;
  for (int tile = 0; tile < 8; tile++) {
    __syncthreads();
    for (int i = threadIdx.x; i < 16 * 128; i += 256) {
      int r = i >> 7, c4 = i & 127;
      ((float4*)hs[r])[c4] =
          ((const float4*)(hcat + (size_t)(b * N_ + n0 + tile * 16 + r) * 512))[c4];
    }
    __syncthreads();
    float acc[16];
#pragma unroll
    for (int t = 0; t < 16; t++) acc[t] = 0.0f;
    for (int cg = 0; cg < 512; cg += 4) {
      float4 w = *(const float4*)(wr + cg);
#pragma unroll
      for (int t = 0; t < 16; t++) {
        float4 h = *(const float4*)(&hs[t][cg]);
        acc[t] += w.x * h.x + w.y * h.y + w.z * h.z + w.w * h.w;
      }
    }
#pragma unroll
    for (int t = 0; t < 16; t++) best = fmaxf(best, acc[t]);
  }
  part[(size_t)(b * 16 + blockIdx.y) * 1024 + o] = best;
}

__global__ void final_reduce(const float* __restrict__ part, const float* __restrict__ bf,
                             float* __restrict__ out) {
  int i = blockIdx.x * 256 + threadIdx.x;
  if (i >= B_ * 1024) return;
  int b = i >> 10, o = i & 1023;
  float m = -3.4e38f;
  for (int s = 0; s < 16; s++) m = fmaxf(m, part[(size_t)(b * 16 + s) * 1024 + o]);
  out[i] = lrelu(m + bf[o]);
}

extern "C" void kernel_launch(void* const* d_in, const int* in_sizes, int n_in, void* d_out,
                              int out_size, void* d_ws, size_t ws_size, hipStream_t stream) {
  (void)in_sizes; (void)n_in; (void)out_size; (void)ws_size;
  const float* x = (const float*)d_in[0];
  const float* W1 = (const float*)d_in[1];
  const float* b1 = (const float*)d_in[2];
  const float* W2 = (const float*)d_in[3];
  const float* b2 = (const float*)d_in[4];
  const float* W3 = (const float*)d_in[5];
  const float* b3 = (const float*)d_in[6];
  const float* W4 = (const float*)d_in[7];
  const float* b4 = (const float*)d_in[8];
  const float* Wf = (const float*)d_in[9];
  const float* bf = (const float*)d_in[10];

  float* ws = (float*)d_ws;
  float* hcat = ws;                          // B*N*512 floats (32 MB)
  float* P = hcat + (size_t)B_ * N_ * 512;   // B*N*512 floats (32 MB)
  int* idx = (int*)(P + (size_t)B_ * N_ * 512);  // B*N*20 ints
  float* Wp = (float*)(idx + (size_t)B_ * N_ * K_);  // up to 512*128 floats
  float* part = Wp + 512 * 128;              // 8*16*1024 floats
  float* out = (float*)d_out;

  dim3 knng(N_ / 8, B_);

  // Layer 1: C=3 -> O=64, input x (stride 3), out hcat[:, 0:64)
  prep_wp<<<(2 * 64 * 3 + 255) / 256, 256, 0, stream>>>(W1, Wp, 64, 3);
  knn_kernel<3><<<knng, 256, 0, stream>>>(x, 3, idx);
  proj_kernel<3, 128><<<dim3(B_ * N_ / 16, 1), 128, 0, stream>>>(x, 3, Wp, P);
  combine_kernel<64><<<B_ * N_, 64, 0, stream>>>(P, idx, b1, hcat + 0);

  // Layer 2: C=64 -> O=64, input hcat[:,0:64), out hcat[:, 64:128)
  prep_wp<<<(2 * 64 * 64 + 255) / 256, 256, 0, stream>>>(W2, Wp, 64, 64);
  knn_kernel<64><<<knng, 256, 0, stream>>>(hcat + 0, 512, idx);
  proj_kernel<64, 128><<<dim3(B_ * N_ / 16, 1), 128, 0, stream>>>(hcat + 0, 512, Wp, P);
  combine_kernel<64><<<B_ * N_, 64, 0, stream>>>(P, idx, b2, hcat + 64);

  // Layer 3: C=64 -> O=128, input hcat[:,64:128), out hcat[:, 128:256)
  prep_wp<<<(2 * 128 * 64 + 255) / 256, 256, 0, stream>>>(W3, Wp, 128, 64);
  knn_kernel<64><<<knng, 256, 0, stream>>>(hcat + 64, 512, idx);
  proj_kernel<64, 256><<<dim3(B_ * N_ / 16, 1), 256, 0, stream>>>(hcat + 64, 512, Wp, P);
  combine_kernel<128><<<B_ * N_, 128, 0, stream>>>(P, idx, b3, hcat + 128);

  // Layer 4: C=128 -> O=256, input hcat[:,128:256), out hcat[:, 256:512)
  prep_wp<<<(2 * 256 * 128 + 255) / 256, 256, 0, stream>>>(W4, Wp, 256, 128);
  knn_kernel<128><<<knng, 256, 0, stream>>>(hcat + 128, 512, idx);
  proj_kernel<128, 512><<<dim3(B_ * N_ / 16, 2), 256, 0, stream>>>(hcat + 128, 512, Wp, P);
  combine_kernel<256><<<B_ * N_, 256, 0, stream>>>(P, idx, b4, hcat + 256);

  // Final 1x1 conv (16384x512 @ 512x1024) + global max over N
  final_kernel<<<dim3(4, 16, B_), 256, 0, stream>>>(hcat, Wf, part);
  final_reduce<<<(B_ * 1024 + 255) / 256, 256, 0, stream>>>(part, bf, out);
}

// Round 2
// 1968.854 us; speedup vs baseline: 1.1425x; 1.1425x over previous
//
#include <hip/hip_runtime.h>

constexpr int B_ = 8;
constexpr int N_ = 2048;
constexpr int K_ = 20;
constexpr float SLOPE_ = 0.2f;

typedef __attribute__((ext_vector_type(8))) short bf16x8;
typedef __attribute__((ext_vector_type(4))) float f32x4;

__device__ __forceinline__ float lrelu(float v) { return v > 0.0f ? v : SLOPE_ * v; }

__device__ __forceinline__ void async16(const void* g, void* l) {
  __builtin_amdgcn_global_load_lds((const __attribute__((address_space(1))) unsigned int*)g,
                                   (__attribute__((address_space(3))) unsigned int*)l, 16, 0, 0);
}

// Build Wp[2O x C]: rows [0,O) = Wd = W[:, :C]; rows [O,2O) = Wc - Wd
__global__ void prep_wp(const float* __restrict__ W, float* __restrict__ Wp, int O, int C) {
  int i = blockIdx.x * 256 + threadIdx.x;
  if (i >= 2 * O * C) return;
  int o = i / C, c = i - o * C;
  if (o < O)
    Wp[i] = W[o * 2 * C + c];
  else
    Wp[i] = W[(o - O) * 2 * C + C + c] - W[(o - O) * 2 * C + c];
}

// fp32 -> bf16 (RNE), vectorized x4
__global__ void cvt_bf16(const float4* __restrict__ src, ushort4* __restrict__ dst, int n4) {
  int i = blockIdx.x * 256 + threadIdx.x;
  if (i >= n4) return;
  float4 v = src[i];
  ushort4 o;
  unsigned u;
  u = __float_as_uint(v.x); u += 0x7fff + ((u >> 16) & 1); o.x = u >> 16;
  u = __float_as_uint(v.y); u += 0x7fff + ((u >> 16) & 1); o.y = u >> 16;
  u = __float_as_uint(v.z); u += 0x7fff + ((u >> 16) & 1); o.z = u >> 16;
  u = __float_as_uint(v.w); u += 0x7fff + ((u >> 16) & 1); o.w = u >> 16;
  dst[i] = o;
}

// kNN v2: 8 queries/block, 256 threads. Distance phase as before (8q x 8m regs).
// Then transpose via LDS (4 chunks, 8 barriers total) so each wave owns 2 queries
// with all 2048 candidates in registers; top-20 extraction is wave-local (0 barriers).
template <int C>
__global__ __launch_bounds__(256) void knn_kernel(const float* __restrict__ xin, int stride,
                                                  int* __restrict__ idxo) {
  const int b = blockIdx.y;
  const int q0 = blockIdx.x * 8;
  const int tid = threadIdx.x;
  __shared__ float qf[8][C];
  __shared__ float d2s[8][512];

  for (int i = tid; i < 8 * C; i += 256) {
    int q = i / C, c = i - q * C;
    qf[q][c] = xin[(size_t)(b * N_ + q0 + q) * stride + c];
  }
  __syncthreads();

  float d2r[8][8];  // [q][j], m = j*256 + tid
  const float* xb = xin + (size_t)b * N_ * stride;
#pragma unroll
  for (int j = 0; j < 8; j++) {
    const int m = j * 256 + tid;
    const float* xr = xb + (size_t)m * stride;
    float acc[8];
#pragma unroll
    for (int q = 0; q < 8; q++) acc[q] = 0.0f;
    if constexpr (C % 4 == 0) {
      for (int cg = 0; cg < C; cg += 4) {
        float4 xv = *(const float4*)(xr + cg);
#pragma unroll
        for (int q = 0; q < 8; q++) {
          float4 qv = *(const float4*)(&qf[q][cg]);
          float a0 = xv.x - qv.x, a1 = xv.y - qv.y, a2 = xv.z - qv.z, a3 = xv.w - qv.w;
          acc[q] += a0 * a0 + a1 * a1 + a2 * a2 + a3 * a3;
        }
      }
    } else {
      for (int c = 0; c < C; c++) {
        float xv = xr[c];
#pragma unroll
        for (int q = 0; q < 8; q++) {
          float d = xv - qf[q][c];
          acc[q] += d * d;
        }
      }
    }
#pragma unroll
    for (int q = 0; q < 8; q++) d2r[q][j] = acc[q];
  }

  const int w = tid >> 6;
  const int lane = tid & 63;
  float r2[2][32];  // wave-owned: r2[s][i] = d2 of m = 512*(i>>3) + 64*(i&7) + lane, q = 2w+s

  for (int ch = 0; ch < 4; ch++) {
    __syncthreads();
#pragma unroll
    for (int q = 0; q < 8; q++) {
      d2s[q][tid] = d2r[q][2 * ch];
      d2s[q][256 + tid] = d2r[q][2 * ch + 1];
    }
    __syncthreads();
#pragma unroll
    for (int s = 0; s < 2; s++) {
      const int q = 2 * w + s;
#pragma unroll
      for (int t = 0; t < 8; t++) r2[s][8 * ch + t] = d2s[q][t * 64 + lane];
    }
  }

#pragma unroll
  for (int s = 0; s < 2; s++) {
    const int q = 2 * w + s;
    int* outp = idxo + (size_t)(b * N_ + q0 + q) * K_;
    for (int t = 0; t < K_; t++) {
      unsigned long long loc = ~0ull;
#pragma unroll
      for (int i = 0; i < 32; i++) {
        int m = 512 * (i >> 3) + 64 * (i & 7) + lane;
        unsigned long long u =
            ((unsigned long long)__float_as_uint(r2[s][i]) << 32) | (unsigned)m;
        loc = u < loc ? u : loc;
      }
#pragma unroll
      for (int off = 32; off > 0; off >>= 1) {
        unsigned long long v = __shfl_xor(loc, off, 64);
        loc = v < loc ? v : loc;
      }
      const int mwin = (int)(unsigned)(loc & 0xffffffffull);
      if (lane == 0) outp[t] = mwin;
      if ((mwin & 63) == lane)
        r2[s][(mwin >> 9) * 8 + ((mwin >> 6) & 7)] = __int_as_float(0x7f800000);
    }
  }
}

// P[row, o'] = sum_c h[row, c] * Wp[o', c]   for o' in [0, 2O)
template <int C, int O2>
__global__ void proj_kernel(const float* __restrict__ hin, int stride,
                            const float* __restrict__ Wp, float* __restrict__ P) {
  const int nt = blockIdx.x * 16;
  const int o = blockIdx.y * blockDim.x + threadIdx.x;
  __shared__ float hs[16][C];
  for (int i = threadIdx.x; i < 16 * C; i += blockDim.x) {
    int r = i / C, c = i - r * C;
    hs[r][c] = hin[(size_t)(nt + r) * stride + c];
  }
  __syncthreads();
  float acc[16];
#pragma unroll
  for (int t = 0; t < 16; t++) acc[t] = 0.0f;
  const float* wr = Wp + (size_t)o * C;
  if constexpr (C % 4 == 0) {
    for (int cg = 0; cg < C; cg += 4) {
      float4 w = *(const float4*)(wr + cg);
#pragma unroll
      for (int t = 0; t < 16; t++) {
        float4 h = *(const float4*)(&hs[t][cg]);
        acc[t] += w.x * h.x + w.y * h.y + w.z * h.z + w.w * h.w;
      }
    }
  } else {
    for (int c = 0; c < C; c++) {
      float w = wr[c];
#pragma unroll
      for (int t = 0; t < 16; t++) acc[t] += w * hs[t][c];
    }
  }
#pragma unroll
  for (int t = 0; t < 16; t++) P[(size_t)(nt + t) * O2 + o] = acc[t];
}

// h_out[row, o] = lrelu( max_k P[b*N + idx[k], o] + P[row, O + o] + bias[o] )
template <int O>
__global__ void combine_kernel(const float* __restrict__ P, const int* __restrict__ idxo,
                               const float* __restrict__ bias, float* __restrict__ hout) {
  const int row = blockIdx.x;
  const int o = threadIdx.x;
  __shared__ int idxs[K_];
  if (o < K_) idxs[o] = idxo[(size_t)row * K_ + o];
  __syncthreads();
  const int base_row = (row >> 11) << 11;
  float g = -3.4e38f;
#pragma unroll
  for (int k = 0; k < K_; k++) {
    float v = P[(size_t)(base_row + idxs[k]) * (2 * O) + o];
    g = fmaxf(g, v);
  }
  float ba = P[(size_t)row * (2 * O) + O + o];
  hout[(size_t)row * 512 + o] = lrelu(g + ba + bias[o]);
}

// Final GEMM: C[m,n] = sum_k hcat_bf[m,k] * Wf_bf[n,k]; epilogue = max over the
// block's 128 m-rows -> part[(b*16 + mblk%16)*1024 + n]. m97-style: 128x128 tile,
// BK=32, global_load_lds(16B), 16x16x32 bf16 MFMA, 4 waves in 2x2 grid.
__global__ __launch_bounds__(256) void gemm_final(const unsigned short* __restrict__ A,
                                                  const unsigned short* __restrict__ Bw,
                                                  float* __restrict__ part) {
  const int m0 = blockIdx.x * 128;
  const int n0 = blockIdx.y * 128;
  const int tid = threadIdx.x;
  const int w = tid >> 6, lane = tid & 63;
  const int wm = w & 1, wn = w >> 1;

  __shared__ unsigned short lA[128 * 32];
  __shared__ unsigned short lB[128 * 32];
  __shared__ float ldsred[2][128];

  // staging: wave w, issue i covers tile rows (w*2+i)*16 .. +16; lane -> row (lane>>2), kseg (lane&3)
  const int r0 = (w * 2 + 0) * 16 + (lane >> 2);
  const int r1 = (w * 2 + 1) * 16 + (lane >> 2);
  const int ks = (lane & 3) * 8;
  const unsigned short* a0 = A + (size_t)(m0 + r0) * 512 + ks;
  const unsigned short* a1 = A + (size_t)(m0 + r1) * 512 + ks;
  const unsigned short* b0 = Bw + (size_t)(n0 + r0) * 512 + ks;
  const unsigned short* b1 = Bw + (size_t)(n0 + r1) * 512 + ks;
  unsigned short* lA0 = lA + (w * 2 + 0) * 512;
  unsigned short* lA1 = lA + (w * 2 + 1) * 512;
  unsigned short* lB0 = lB + (w * 2 + 0) * 512;
  unsigned short* lB1 = lB + (w * 2 + 1) * 512;

  f32x4 acc[4][4] = {};
  const int ka = (lane >> 4) * 8;

  for (int k0 = 0; k0 < 512; k0 += 32) {
    __syncthreads();
    async16(a0 + k0, lA0);
    async16(a1 + k0, lA1);
    async16(b0 + k0, lB0);
    async16(b1 + k0, lB1);
    __syncthreads();
    bf16x8 af[4], bfr[4];
#pragma unroll
    for (int mt = 0; mt < 4; mt++)
      af[mt] = *(const bf16x8*)&lA[(wm * 64 + mt * 16 + (lane & 15)) * 32 + ka];
#pragma unroll
    for (int nt = 0; nt < 4; nt++)
      bfr[nt] = *(const bf16x8*)&lB[(wn * 64 + nt * 16 + (lane & 15)) * 32 + ka];
#pragma unroll
    for (int mt = 0; mt < 4; mt++)
#pragma unroll
      for (int nt = 0; nt < 4; nt++)
        acc[mt][nt] = __builtin_amdgcn_mfma_f32_16x16x32_bf16(af[mt], bfr[nt], acc[mt][nt], 0, 0, 0);
  }

  // epilogue: per-column max over this block's 128 rows
#pragma unroll
  for (int nt = 0; nt < 4; nt++) {
    float v = -3.4e38f;
#pragma unroll
    for (int mt = 0; mt < 4; mt++)
#pragma unroll
      for (int r = 0; r < 4; r++) v = fmaxf(v, acc[mt][nt][r]);
    v = fmaxf(v, __shfl_xor(v, 16, 64));
    v = fmaxf(v, __shfl_xor(v, 32, 64));
    if (lane < 16) ldsred[wm][wn * 64 + nt * 16 + lane] = v;
  }
  __syncthreads();
  if (tid < 128) {
    float v = fmaxf(ldsred[0][tid], ldsred[1][tid]);
    const int b = blockIdx.x >> 4, s5 = blockIdx.x & 15;
    part[(size_t)(b * 16 + s5) * 1024 + n0 + tid] = v;
  }
}

__global__ void final_reduce(const float* __restrict__ part, const float* __restrict__ bf,
                             float* __restrict__ out) {
  int i = blockIdx.x * 256 + threadIdx.x;
  if (i >= B_ * 1024) return;
  int b = i >> 10, o = i & 1023;
  float m = -3.4e38f;
  for (int s = 0; s < 16; s++) m = fmaxf(m, part[(size_t)(b * 16 + s) * 1024 + o]);
  out[i] = lrelu(m + bf[o]);
}

extern "C" void kernel_launch(void* const* d_in, const int* in_sizes, int n_in, void* d_out,
                              int out_size, void* d_ws, size_t ws_size, hipStream_t stream) {
  (void)in_sizes; (void)n_in; (void)out_size; (void)ws_size;
  const float* x = (const float*)d_in[0];
  const float* W1 = (const float*)d_in[1];
  const float* b1 = (const float*)d_in[2];
  const float* W2 = (const float*)d_in[3];
  const float* b2 = (const float*)d_in[4];
  const float* W3 = (const float*)d_in[5];
  const float* b3 = (const float*)d_in[6];
  const float* W4 = (const float*)d_in[7];
  const float* b4 = (const float*)d_in[8];
  const float* Wf = (const float*)d_in[9];
  const float* bf = (const float*)d_in[10];

  float* ws = (float*)d_ws;
  float* hcat = ws;                               // B*N*512 floats (32 MB)
  float* P = hcat + (size_t)B_ * N_ * 512;        // B*N*512 floats (32 MB)
  int* idx = (int*)(P + (size_t)B_ * N_ * 512);   // B*N*20 ints
  float* Wp = (float*)(idx + (size_t)B_ * N_ * K_);
  float* part = Wp + 512 * 128;                   // 8*16*1024 floats
  float* out = (float*)d_out;
  // bf16 buffers alias P (dead after layer-4 combine)
  unsigned short* hcat_bf = (unsigned short*)P;                      // 8.4M bf16
  unsigned short* Wf_bf = hcat_bf + (size_t)B_ * N_ * 512;           // 524288 bf16

  dim3 knng(N_ / 8, B_);

  // Layer 1: C=3 -> O=64
  prep_wp<<<(2 * 64 * 3 + 255) / 256, 256, 0, stream>>>(W1, Wp, 64, 3);
  knn_kernel<3><<<knng, 256, 0, stream>>>(x, 3, idx);
  proj_kernel<3, 128><<<dim3(B_ * N_ / 16, 1), 128, 0, stream>>>(x, 3, Wp, P);
  combine_kernel<64><<<B_ * N_, 64, 0, stream>>>(P, idx, b1, hcat + 0);

  // Layer 2: C=64 -> O=64
  prep_wp<<<(2 * 64 * 64 + 255) / 256, 256, 0, stream>>>(W2, Wp, 64, 64);
  knn_kernel<64><<<knng, 256, 0, stream>>>(hcat + 0, 512, idx);
  proj_kernel<64, 128><<<dim3(B_ * N_ / 16, 1), 128, 0, stream>>>(hcat + 0, 512, Wp, P);
  combine_kernel<64><<<B_ * N_, 64, 0, stream>>>(P, idx, b2, hcat + 64);

  // Layer 3: C=64 -> O=128
  prep_wp<<<(2 * 128 * 64 + 255) / 256, 256, 0, stream>>>(W3, Wp, 128, 64);
  knn_kernel<64><<<knng, 256, 0, stream>>>(hcat + 64, 512, idx);
  proj_kernel<64, 256><<<dim3(B_ * N_ / 16, 1), 256, 0, stream>>>(hcat + 64, 512, Wp, P);
  combine_kernel<128><<<B_ * N_, 128, 0, stream>>>(P, idx, b3, hcat + 128);

  // Layer 4: C=128 -> O=256
  prep_wp<<<(2 * 256 * 128 + 255) / 256, 256, 0, stream>>>(W4, Wp, 256, 128);
  knn_kernel<128><<<knng, 256, 0, stream>>>(hcat + 128, 512, idx);
  proj_kernel<128, 512><<<dim3(B_ * N_ / 16, 2), 256, 0, stream>>>(hcat + 128, 512, Wp, P);
  combine_kernel<256><<<B_ * N_, 256, 0, stream>>>(P, idx, b4, hcat + 256);

  // Final 1x1 conv via bf16 MFMA + fused max-over-rows
  cvt_bf16<<<(B_ * N_ * 512 / 4 + 255) / 256, 256, 0, stream>>>(
      (const float4*)hcat, (ushort4*)hcat_bf, B_ * N_ * 512 / 4);
  cvt_bf16<<<(1024 * 512 / 4 + 255) / 256, 256, 0, stream>>>(
      (const float4*)Wf, (ushort4*)Wf_bf, 1024 * 512 / 4);
  gemm_final<<<dim3(128, 8), 256, 0, stream>>>(hcat_bf, Wf_bf, part);
  final_reduce<<<(B_ * 1024 + 255) / 256, 256, 0, stream>>>(part, bf, out);
}

// Round 3
// 1270.194 us; speedup vs baseline: 1.7709x; 1.5500x over previous
//
#include <hip/hip_runtime.h>

constexpr int B_ = 8;
constexpr int N_ = 2048;
constexpr int K_ = 20;
constexpr float SLOPE_ = 0.2f;

typedef __attribute__((ext_vector_type(8))) short bf16x8;
typedef __attribute__((ext_vector_type(4))) float f32x4;

__device__ __forceinline__ float lrelu(float v) { return v > 0.0f ? v : SLOPE_ * v; }

__device__ __forceinline__ void async16(const void* g, void* l) {
  __builtin_amdgcn_global_load_lds((const __attribute__((address_space(1))) unsigned int*)g,
                                   (__attribute__((address_space(3))) unsigned int*)l, 16, 0, 0);
}

// Build Wp[2O x C]: rows [0,O) = Wd = W[:, :C]; rows [O,2O) = Wc - Wd
__global__ void prep_wp(const float* __restrict__ W, float* __restrict__ Wp, int O, int C) {
  int i = blockIdx.x * 256 + threadIdx.x;
  if (i >= 2 * O * C) return;
  int o = i / C, c = i - o * C;
  if (o < O)
    Wp[i] = W[o * 2 * C + c];
  else
    Wp[i] = W[(o - O) * 2 * C + C + c] - W[(o - O) * 2 * C + c];
}

// fp32 -> bf16 (RNE), vectorized x4
__global__ void cvt_bf16(const float4* __restrict__ src, ushort4* __restrict__ dst, int n4) {
  int i = blockIdx.x * 256 + threadIdx.x;
  if (i >= n4) return;
  float4 v = src[i];
  ushort4 o;
  unsigned u;
  u = __float_as_uint(v.x); u += 0x7fff + ((u >> 16) & 1); o.x = u >> 16;
  u = __float_as_uint(v.y); u += 0x7fff + ((u >> 16) & 1); o.y = u >> 16;
  u = __float_as_uint(v.z); u += 0x7fff + ((u >> 16) & 1); o.z = u >> 16;
  u = __float_as_uint(v.w); u += 0x7fff + ((u >> 16) & 1); o.w = u >> 16;
  dst[i] = o;
}

// kNN: 8 queries/block, 256 threads. Distance phase: 8q x 8m in registers.
// Transpose via LDS (fully unrolled -> registers only) so each wave owns 2 queries
// with all 2048 candidates in regs (32/lane). Top-20: per-t rebuild local min
// (static unroll), u64 butterfly, static compare-poison. NO dynamic reg indexing.
template <int C>
__global__ __launch_bounds__(256) void knn_kernel(const float* __restrict__ xin, int stride,
                                                  int* __restrict__ idxo) {
  const int b = blockIdx.y;
  const int q0 = blockIdx.x * 8;
  const int tid = threadIdx.x;
  __shared__ float qf[8][C];
  __shared__ float d2s[8][512];

  for (int i = tid; i < 8 * C; i += 256) {
    int q = i / C, c = i - q * C;
    qf[q][c] = xin[(size_t)(b * N_ + q0 + q) * stride + c];
  }
  __syncthreads();

  float d2r[8][8];  // [q][j], m = j*256 + tid
  const float* xb = xin + (size_t)b * N_ * stride;
#pragma unroll
  for (int j = 0; j < 8; j++) {
    const int m = j * 256 + tid;
    const float* xr = xb + (size_t)m * stride;
    float acc[8];
#pragma unroll
    for (int q = 0; q < 8; q++) acc[q] = 0.0f;
    if constexpr (C % 4 == 0) {
      for (int cg = 0; cg < C; cg += 4) {
        float4 xv = *(const float4*)(xr + cg);
#pragma unroll
        for (int q = 0; q < 8; q++) {
          float4 qv = *(const float4*)(&qf[q][cg]);
          float a0 = xv.x - qv.x, a1 = xv.y - qv.y, a2 = xv.z - qv.z, a3 = xv.w - qv.w;
          acc[q] += a0 * a0 + a1 * a1 + a2 * a2 + a3 * a3;
        }
      }
    } else {
      for (int c = 0; c < C; c++) {
        float xv = xr[c];
#pragma unroll
        for (int q = 0; q < 8; q++) {
          float d = xv - qf[q][c];
          acc[q] += d * d;
        }
      }
    }
#pragma unroll
    for (int q = 0; q < 8; q++) d2r[q][j] = acc[q];
  }

  const int w = tid >> 6;
  const int lane = tid & 63;
  float r2[2][32];  // r2[s][i] = d2 of m = 512*(i>>3) + 64*(i&7) + lane, query q = 2w+s

#pragma unroll
  for (int ch = 0; ch < 4; ch++) {
    __syncthreads();
#pragma unroll
    for (int q = 0; q < 8; q++) {
      d2s[q][tid] = d2r[q][2 * ch];
      d2s[q][256 + tid] = d2r[q][2 * ch + 1];
    }
    __syncthreads();
#pragma unroll
    for (int s = 0; s < 2; s++) {
      const int q = 2 * w + s;
#pragma unroll
      for (int t = 0; t < 8; t++) r2[s][8 * ch + t] = d2s[q][t * 64 + lane];
    }
  }

#pragma unroll
  for (int s = 0; s < 2; s++) {
    const int q = 2 * w + s;
    int* outp = idxo + (size_t)(b * N_ + q0 + q) * K_;
    for (int t = 0; t < K_; t++) {
      // rebuild local min (static unroll, registers only)
      unsigned long long loc = ~0ull;
#pragma unroll
      for (int i = 0; i < 32; i++) {
        int m = 512 * (i >> 3) + 64 * (i & 7) + lane;
        unsigned long long u =
            ((unsigned long long)__float_as_uint(r2[s][i]) << 32) | (unsigned)m;
        loc = u < loc ? u : loc;
      }
      // wave butterfly min
#pragma unroll
      for (int off = 32; off > 0; off >>= 1) {
        unsigned long long v = __shfl_xor(loc, off, 64);
        loc = v < loc ? v : loc;
      }
      const int mwin = (int)(unsigned)(loc & 0xffffffffull);
      if (lane == 0) outp[t] = mwin;
      // static compare-poison (stays in registers)
#pragma unroll
      for (int i = 0; i < 32; i++) {
        int m = 512 * (i >> 3) + 64 * (i & 7) + lane;
        if (m == mwin) r2[s][i] = __int_as_float(0x7f800000);
      }
    }
  }
}

// P[row, o'] = sum_c h[row, c] * Wp[o', c]   for o' in [0, 2O)
template <int C, int O2>
__global__ void proj_kernel(const float* __restrict__ hin, int stride,
                            const float* __restrict__ Wp, float* __restrict__ P) {
  const int nt = blockIdx.x * 16;
  const int o = blockIdx.y * blockDim.x + threadIdx.x;
  __shared__ float hs[16][C];
  for (int i = threadIdx.x; i < 16 * C; i += blockDim.x) {
    int r = i / C, c = i - r * C;
    hs[r][c] = hin[(size_t)(nt + r) * stride + c];
  }
  __syncthreads();
  float acc[16];
#pragma unroll
  for (int t = 0; t < 16; t++) acc[t] = 0.0f;
  const float* wr = Wp + (size_t)o * C;
  if constexpr (C % 4 == 0) {
    for (int cg = 0; cg < C; cg += 4) {
      float4 w = *(const float4*)(wr + cg);
#pragma unroll
      for (int t = 0; t < 16; t++) {
        float4 h = *(const float4*)(&hs[t][cg]);
        acc[t] += w.x * h.x + w.y * h.y + w.z * h.z + w.w * h.w;
      }
    }
  } else {
    for (int c = 0; c < C; c++) {
      float w = wr[c];
#pragma unroll
      for (int t = 0; t < 16; t++) acc[t] += w * hs[t][c];
    }
  }
#pragma unroll
  for (int t = 0; t < 16; t++) P[(size_t)(nt + t) * O2 + o] = acc[t];
}

// h_out[row, o] = lrelu( max_k P[b*N + idx[k], o] + P[row, O + o] + bias[o] )
template <int O>
__global__ void combine_kernel(const float* __restrict__ P, const int* __restrict__ idxo,
                               const float* __restrict__ bias, float* __restrict__ hout) {
  const int row = blockIdx.x;
  const int o = threadIdx.x;
  __shared__ int idxs[K_];
  if (o < K_) idxs[o] = idxo[(size_t)row * K_ + o];
  __syncthreads();
  const int base_row = (row >> 11) << 11;
  float g = -3.4e38f;
#pragma unroll
  for (int k = 0; k < K_; k++) {
    float v = P[(size_t)(base_row + idxs[k]) * (2 * O) + o];
    g = fmaxf(g, v);
  }
  float ba = P[(size_t)row * (2 * O) + O + o];
  hout[(size_t)row * 512 + o] = lrelu(g + ba + bias[o]);
}

// Final GEMM: 128x128 tile, BK=32, global_load_lds(16B), 16x16x32 bf16 MFMA,
// epilogue = max over the block's 128 m-rows -> part.
__global__ __launch_bounds__(256) void gemm_final(const unsigned short* __restrict__ A,
                                                  const unsigned short* __restrict__ Bw,
                                                  float* __restrict__ part) {
  const int m0 = blockIdx.x * 128;
  const int n0 = blockIdx.y * 128;
  const int tid = threadIdx.x;
  const int w = tid >> 6, lane = tid & 63;
  const int wm = w & 1, wn = w >> 1;

  __shared__ unsigned short lA[128 * 32];
  __shared__ unsigned short lB[128 * 32];
  __shared__ float ldsred[2][128];

  const int r0 = (w * 2 + 0) * 16 + (lane >> 2);
  const int r1 = (w * 2 + 1) * 16 + (lane >> 2);
  const int ks = (lane & 3) * 8;
  const unsigned short* a0 = A + (size_t)(m0 + r0) * 512 + ks;
  const unsigned short* a1 = A + (size_t)(m0 + r1) * 512 + ks;
  const unsigned short* b0 = Bw + (size_t)(n0 + r0) * 512 + ks;
  const unsigned short* b1 = Bw + (size_t)(n0 + r1) * 512 + ks;
  unsigned short* lA0 = lA + (w * 2 + 0) * 512;
  unsigned short* lA1 = lA + (w * 2 + 1) * 512;
  unsigned short* lB0 = lB + (w * 2 + 0) * 512;
  unsigned short* lB1 = lB + (w * 2 + 1) * 512;

  f32x4 acc[4][4] = {};
  const int ka = (lane >> 4) * 8;

  for (int k0 = 0; k0 < 512; k0 += 32) {
    __syncthreads();
    async16(a0 + k0, lA0);
    async16(a1 + k0, lA1);
    async16(b0 + k0, lB0);
    async16(b1 + k0, lB1);
    __syncthreads();
    bf16x8 af[4], bfr[4];
#pragma unroll
    for (int mt = 0; mt < 4; mt++)
      af[mt] = *(const bf16x8*)&lA[(wm * 64 + mt * 16 + (lane & 15)) * 32 + ka];
#pragma unroll
    for (int nt = 0; nt < 4; nt++)
      bfr[nt] = *(const bf16x8*)&lB[(wn * 64 + nt * 16 + (lane & 15)) * 32 + ka];
#pragma unroll
    for (int mt = 0; mt < 4; mt++)
#pragma unroll
      for (int nt = 0; nt < 4; nt++)
        acc[mt][nt] = __builtin_amdgcn_mfma_f32_16x16x32_bf16(af[mt], bfr[nt], acc[mt][nt], 0, 0, 0);
  }

#pragma unroll
  for (int nt = 0; nt < 4; nt++) {
    float v = -3.4e38f;
#pragma unroll
    for (int mt = 0; mt < 4; mt++)
#pragma unroll
      for (int r = 0; r < 4; r++) v = fmaxf(v, acc[mt][nt][r]);
    v = fmaxf(v, __shfl_xor(v, 16, 64));
    v = fmaxf(v, __shfl_xor(v, 32, 64));
    if (lane < 16) ldsred[wm][wn * 64 + nt * 16 + lane] = v;
  }
  __syncthreads();
  if (tid < 128) {
    float v = fmaxf(ldsred[0][tid], ldsred[1][tid]);
    const int b = blockIdx.x >> 4, s5 = blockIdx.x & 15;
    part[(size_t)(b * 16 + s5) * 1024 + n0 + tid] = v;
  }
}

__global__ void final_reduce(const float* __restrict__ part, const float* __restrict__ bf,
                             float* __restrict__ out) {
  int i = blockIdx.x * 256 + threadIdx.x;
  if (i >= B_ * 1024) return;
  int b = i >> 10, o = i & 1023;
  float m = -3.4e38f;
  for (int s = 0; s < 16; s++) m = fmaxf(m, part[(size_t)(b * 16 + s) * 1024 + o]);
  out[i] = lrelu(m + bf[o]);
}

extern "C" void kernel_launch(void* const* d_in, const int* in_sizes, int n_in, void* d_out,
                              int out_size, void* d_ws, size_t ws_size, hipStream_t stream) {
  (void)in_sizes; (void)n_in; (void)out_size; (void)ws_size;
  const float* x = (const float*)d_in[0];
  const float* W1 = (const float*)d_in[1];
  const float* b1 = (const float*)d_in[2];
  const float* W2 = (const float*)d_in[3];
  const float* b2 = (const float*)d_in[4];
  const float* W3 = (const float*)d_in[5];
  const float* b3 = (const float*)d_in[6];
  const float* W4 = (const float*)d_in[7];
  const float* b4 = (const float*)d_in[8];
  const float* Wf = (const float*)d_in[9];
  const float* bf = (const float*)d_in[10];

  float* ws = (float*)d_ws;
  float* hcat = ws;                               // B*N*512 floats (32 MB)
  float* P = hcat + (size_t)B_ * N_ * 512;        // B*N*512 floats (32 MB)
  int* idx = (int*)(P + (size_t)B_ * N_ * 512);   // B*N*20 ints
  float* Wp = (float*)(idx + (size_t)B_ * N_ * K_);
  float* part = Wp + 512 * 128;                   // 8*16*1024 floats
  float* out = (float*)d_out;
  unsigned short* hcat_bf = (unsigned short*)P;   // alias P (dead after layer-4)
  unsigned short* Wf_bf = hcat_bf + (size_t)B_ * N_ * 512;

  dim3 knng(N_ / 8, B_);

  // Layer 1: C=3 -> O=64
  prep_wp<<<(2 * 64 * 3 + 255) / 256, 256, 0, stream>>>(W1, Wp, 64, 3);
  knn_kernel<3><<<knng, 256, 0, stream>>>(x, 3, idx);
  proj_kernel<3, 128><<<dim3(B_ * N_ / 16, 1), 128, 0, stream>>>(x, 3, Wp, P);
  combine_kernel<64><<<B_ * N_, 64, 0, stream>>>(P, idx, b1, hcat + 0);

  // Layer 2: C=64 -> O=64
  prep_wp<<<(2 * 64 * 64 + 255) / 256, 256, 0, stream>>>(W2, Wp, 64, 64);
  knn_kernel<64><<<knng, 256, 0, stream>>>(hcat + 0, 512, idx);
  proj_kernel<64, 128><<<dim3(B_ * N_ / 16, 1), 128, 0, stream>>>(hcat + 0, 512, Wp, P);
  combine_kernel<64><<<B_ * N_, 64, 0, stream>>>(P, idx, b2, hcat + 64);

  // Layer 3: C=64 -> O=128
  prep_wp<<<(2 * 128 * 64 + 255) / 256, 256, 0, stream>>>(W3, Wp, 128, 64);
  knn_kernel<64><<<knng, 256, 0, stream>>>(hcat + 64, 512, idx);
  proj_kernel<64, 256><<<dim3(B_ * N_ / 16, 1), 256, 0, stream>>>(hcat + 64, 512, Wp, P);
  combine_kernel<128><<<B_ * N_, 128, 0, stream>>>(P, idx, b3, hcat + 128);

  // Layer 4: C=128 -> O=256
  prep_wp<<<(2 * 256 * 128 + 255) / 256, 256, 0, stream>>>(W4, Wp, 256, 128);
  knn_kernel<128><<<knng, 256, 0, stream>>>(hcat + 128, 512, idx);
  proj_kernel<128, 512><<<dim3(B_ * N_ / 16, 2), 256, 0, stream>>>(hcat + 128, 512, Wp, P);
  combine_kernel<256><<<B_ * N_, 256, 0, stream>>>(P, idx, b4, hcat + 256);

  // Final 1x1 conv via bf16 MFMA + fused max-over-rows
  cvt_bf16<<<(B_ * N_ * 512 / 4 + 255) / 256, 256, 0, stream>>>(
      (const float4*)hcat, (ushort4*)hcat_bf, B_ * N_ * 512 / 4);
  cvt_bf16<<<(1024 * 512 / 4 + 255) / 256, 256, 0, stream>>>(
      (const float4*)Wf, (ushort4*)Wf_bf, 1024 * 512 / 4);
  gemm_final<<<dim3(128, 8), 256, 0, stream>>>(hcat_bf, Wf_bf, part);
  final_reduce<<<(B_ * 1024 + 255) / 256, 256, 0, stream>>>(part, bf, out);
}